// Round 2
// baseline (972.184 us; speedup 1.0000x reference)
//
#include <hip/hip_runtime.h>
#include <stdint.h>

// SelfAttention: B=4, S=4096, D=768, causal, fp32 in/out, bf16 MFMA compute.
// cvt -> qkv GEMM (128x128, 2-barrier) -> scores GEMM (256x256 tile, 512 thr,
// DOUBLE-buffered BK=32 pipeline, counted vmcnt, 64KB LDS -> 2 blocks/CU,
// exp epilogue, packed causal P tiles) -> PV GEMM (/l epilogue).
// ws layout (bf16 elements):
//   qb  12582912 @ 0
//   kb  12582912 @ 12582912
//   vt  12582912 @ 25165824   [b][e][s] (V transposed)
//   xb  12582912 @ 37748736   (dead after qkv_proj)
//   wb   1769472 @ 50331648   (dead after qkv_proj)
//   pb  34603008 @ 37748736   ALIAS over xb/wb: packed causal P tiles,
//                             tile (b, mt, nt<=mt) at slot b*528+mt(mt+1)/2+nt
//   ls  16384 fp32 @ elem 72351744
#define SEQ 4096
#define DIM 768

typedef __attribute__((ext_vector_type(8))) short short8;
typedef __attribute__((ext_vector_type(8))) unsigned short ushort8;
typedef __attribute__((ext_vector_type(4))) unsigned short ushort4v;
typedef __attribute__((ext_vector_type(4))) float fx4;
typedef unsigned short ushort;

#define MFMA16(a, b, c) __builtin_amdgcn_mfma_f32_16x16x32_bf16((a), (b), (c), 0, 0, 0)

__device__ __forceinline__ ushort f2bf(float f) {
  union { float f; unsigned int u; } v; v.f = f;
  return (ushort)((v.u + 0x7fffu + ((v.u >> 16) & 1u)) >> 16);
}
__device__ __forceinline__ float bf2f(ushort u) {
  union { unsigned int u; float f; } v; v.u = ((unsigned int)u) << 16;
  return v.f;
}
__device__ __forceinline__ void gload_lds16(const ushort* g, ushort* l) {
  __builtin_amdgcn_global_load_lds(
      (const __attribute__((address_space(1))) void*)g,
      (__attribute__((address_space(3))) void*)l, 16, 0, 0);
}

// ---------- kernel 0: fused fp32->bf16 casts + ls zero ----------
__global__ void cvt_all(const float* __restrict__ x, const float* __restrict__ wq,
                        const float* __restrict__ wk, const float* __restrict__ wv,
                        ushort* __restrict__ xb, ushort* __restrict__ wb,
                        float* __restrict__ ls) {
  const int bid = blockIdx.x;
  if (bid < 6144) {
    if (bid < 64) ls[bid * 256 + threadIdx.x] = 0.0f;
    const int i = (bid * 256 + threadIdx.x) * 8;
    fx4 a = *(const fx4*)(x + i);
    fx4 b = *(const fx4*)(x + i + 4);
    ushort8 o;
#pragma unroll
    for (int c = 0; c < 4; c++) { o[c] = f2bf(a[c]); o[c + 4] = f2bf(b[c]); }
    *(ushort8*)(xb + i) = o;
  } else {
    const int i = ((bid - 6144) * 256 + threadIdx.x) * 8;
    const int which = i / (DIM * DIM);
    const int off = i - which * (DIM * DIM);
    const float* src = (which == 0) ? wq : (which == 1) ? wk : wv;
    fx4 a = *(const fx4*)(src + off);
    fx4 b = *(const fx4*)(src + off + 4);
    ushort8 o;
#pragma unroll
    for (int c = 0; c < 4; c++) { o[c] = f2bf(a[c]); o[c + 4] = f2bf(b[c]); }
    *(ushort8*)(wb + i) = o;
  }
}

// ---------- kernel 1: QKV projection (128x128 tile, BK=64) ----------
__global__ __launch_bounds__(256, 4)
void qkv_proj(const ushort* __restrict__ xb, const ushort* __restrict__ wb,
              ushort* __restrict__ qb, ushort* __restrict__ kb,
              ushort* __restrict__ vt) {
  __shared__ ushort smem[17408];  // k-loop: As[8192]|Bs[8192]; epilogue 128x136
  ushort* As = smem;
  ushort* Bs = smem + 8192;

  const int mb = blockIdx.x, nb = blockIdx.y;
  const int which = nb / 6;
  const int e0 = (nb % 6) * 128;
  const int m0 = mb * 128;
  const int tid = threadIdx.x;
  const int w = tid >> 6, lane = tid & 63, ln = lane & 15, quad = lane >> 4;
  const int wm = (w >> 1) * 64, wn = (w & 1) * 64;

  const ushort* W = wb + (size_t)which * (DIM * DIM);

  const int c0 = w * 128 + lane;
  const int c1 = c0 + 64;
  const int R0 = c0 >> 2, kl0 = (c0 & 3) ^ ((R0 >> 1) & 3);
  const int R1 = c1 >> 2, kl1 = (c1 & 3) ^ ((R1 >> 1) & 3);
  const ushort* ag0 = xb + (size_t)(m0 + R0) * DIM + kl0 * 8;
  const ushort* ag1 = xb + (size_t)(m0 + R1) * DIM + kl1 * 8;
  const ushort* bg0 = W + (size_t)(e0 + R0) * DIM + kl0 * 8;
  const ushort* bg1 = W + (size_t)(e0 + R1) * DIM + kl1 * 8;
  ushort* al0 = As + (size_t)(w * 128) * 8;
  ushort* al1 = As + (size_t)(w * 128 + 64) * 8;
  ushort* bl0 = Bs + (size_t)(w * 128) * 8;
  ushort* bl1 = Bs + (size_t)(w * 128 + 64) * 8;

  const int sw = quad ^ ((ln >> 1) & 3);
  int aoff[4], boff[4];
#pragma unroll
  for (int i = 0; i < 4; i++) aoff[i] = ((wm + i * 16 + ln) * 4 + sw) * 8;
#pragma unroll
  for (int i = 0; i < 4; i++) boff[i] = ((wn + i * 16 + ln) * 4 + sw) * 8;

  fx4 acc[4][4];
#pragma unroll
  for (int i = 0; i < 4; i++)
#pragma unroll
    for (int j = 0; j < 4; j++) acc[i][j] = (fx4)0.0f;

  for (int kk = 0; kk < DIM; kk += 64) {
    gload_lds16(ag0 + kk, al0);
    gload_lds16(ag1 + kk, al1);
    gload_lds16(ag0 + kk + 32, al0 + 4096);
    gload_lds16(ag1 + kk + 32, al1 + 4096);
    gload_lds16(bg0 + kk, bl0);
    gload_lds16(bg1 + kk, bl1);
    gload_lds16(bg0 + kk + 32, bl0 + 4096);
    gload_lds16(bg1 + kk + 32, bl1 + 4096);
    __syncthreads();
#pragma unroll
    for (int h = 0; h < 2; h++) {
      const int hb = h * 4096;
      short8 af[4], bf[4];
#pragma unroll
      for (int i = 0; i < 4; i++) af[i] = *(const short8*)(As + hb + aoff[i]);
#pragma unroll
      for (int i = 0; i < 4; i++) bf[i] = *(const short8*)(Bs + hb + boff[i]);
#pragma unroll
      for (int i = 0; i < 4; i++)
#pragma unroll
        for (int j = 0; j < 4; j++)
          acc[i][j] = MFMA16(af[i], bf[j], acc[i][j]);
    }
    __syncthreads();
  }

  if (which == 2) {
#pragma unroll
    for (int i = 0; i < 4; i++)
#pragma unroll
      for (int j = 0; j < 4; j++) {
        const int s = m0 + wm + i * 16 + quad * 4;
        const int e = e0 + wn + j * 16 + ln;
        const int bb = s >> 12, si = s & 4095;
        ushort4v p;
#pragma unroll
        for (int r = 0; r < 4; r++) p[r] = f2bf(acc[i][j][r]);
        *(ushort4v*)(vt + ((size_t)bb * DIM + e) * SEQ + si) = p;
      }
  } else {
#pragma unroll
    for (int i = 0; i < 4; i++)
#pragma unroll
      for (int j = 0; j < 4; j++)
#pragma unroll
        for (int r = 0; r < 4; r++)
          smem[(wm + i * 16 + quad * 4 + r) * 136 + wn + j * 16 + ln] =
              f2bf(acc[i][j][r]);
    __syncthreads();
    ushort* dst = (which == 0) ? qb : kb;
#pragma unroll
    for (int p = 0; p < 8; p++) {
      const int tt = p * 256 + tid;
      const int row = tt >> 4, col = (tt & 15) * 8;
      ushort8 v = *(const ushort8*)&smem[row * 136 + col];
      *(ushort8*)(dst + (size_t)(m0 + row) * DIM + e0 + col) = v;
    }
  }
}

// ---------- kernel 2: scores GEMM, 256x256 tile, double-buffered BK=32 -----
// 512 thr = 8 waves (2M x 4N); per-wave 128x64 out, acc[8][4].
// LDS: 2 buffers x 32KB -> 64KB total -> 2 blocks/CU (4 waves/SIMD): barrier
// stalls in one block are covered by the co-resident block (m114 mechanism).
// Pipeline: stage buf[t+1] -> vmcnt(4) (cur buf's loads done, next's 4 stay
// in flight across both barriers) -> barrier -> 12x ds_read_b128 + 32 MFMA
// (compiler interleaves, counted lgkm) -> lgkmcnt(0) -> barrier.
// Last iter: no stage, vmcnt(0) so the epilogue's smem reuse is race-free.
__global__ __launch_bounds__(512, 4)
void attn_scores(const ushort* __restrict__ qb, const ushort* __restrict__ kb,
                 ushort* __restrict__ pb, float* __restrict__ ls) {
  __shared__ ushort smem[32768];  // 64 KiB: 2 x 16384-ushort buffers

  // XCD-aware bijective swizzle: 544 blocks = 8 XCDs x 68
  const int r0 = blockIdx.x;
  const int wg = (r0 & 7) * 68 + (r0 >> 3);
  const int b = wg / 136;
  const int pr = wg - b * 136;
  int mt = (int)(0.5f * (sqrtf(8.0f * pr + 1.0f) - 1.0f));
  while ((mt + 1) * (mt + 2) / 2 <= pr) ++mt;
  while (mt * (mt + 1) / 2 > pr) --mt;
  const int nt = pr - mt * (mt + 1) / 2;
  const int m0 = mt * 256, n0 = nt * 256;

  const int tid = threadIdx.x;
  const int w = tid >> 6, lane = tid & 63, ln = lane & 15, quad = lane >> 4;
  const int wn = (w & 3) * 64;
  const size_t qkbase = (size_t)b * SEQ * DIM;
  const float scale = 0.03608439182435161f;  // 1/sqrt(768)

  // staging: 512 threads cover one 128x32 chunk per gload (slot t: row t>>2,
  // k-group kl = (t&3)^((row>>1)&3); LDS dest linear, source pre-swizzled)
  const int R = tid >> 2;
  const int kl = (tid & 3) ^ ((R >> 1) & 3);
  const ushort* ag0 = qb + qkbase + (size_t)(m0 + R) * DIM + kl * 8;
  const ushort* ag1 = qb + qkbase + (size_t)(m0 + 128 + R) * DIM + kl * 8;
  const ushort* bg0 = kb + qkbase + (size_t)(n0 + R) * DIM + kl * 8;
  const ushort* bg1 = kb + qkbase + (size_t)(n0 + 128 + R) * DIM + kl * 8;
  const int ldsw = w * 512;  // this wave's 1KB slice within a chunk (ushorts)

  // fragment read offsets (ushort units, within one 32KB buffer)
  const int sw = quad ^ ((ln >> 1) & 3);
  const int myh = w >> 2;  // wave's m-half
  int aoff[8], boff[4];
#pragma unroll
  for (int i = 0; i < 8; i++)
    aoff[i] = myh * 4096 + (i * 16 + ln) * 32 + sw * 8;
#pragma unroll
  for (int j = 0; j < 4; j++)
    boff[j] = 8192 + (wn >> 7) * 4096 + ((wn & 127) + j * 16 + ln) * 32 + sw * 8;

  fx4 acc[8][4];
#pragma unroll
  for (int i = 0; i < 8; i++)
#pragma unroll
    for (int j = 0; j < 4; j++) acc[i][j] = (fx4)0.0f;

#define SSTAGE(BUF, KO) do {                                   \
    ushort* Lb = smem + (BUF) * 16384;                         \
    gload_lds16(ag0 + (KO), Lb + ldsw);                        \
    gload_lds16(ag1 + (KO), Lb + 4096 + ldsw);                 \
    gload_lds16(bg0 + (KO), Lb + 8192 + ldsw);                 \
    gload_lds16(bg1 + (KO), Lb + 12288 + ldsw);                \
  } while (0)

#define SPHASE(BUF, VM) do {                                   \
    const ushort* Lb = smem + (BUF) * 16384;                   \
    asm volatile("s_waitcnt vmcnt(" VM ")" ::: "memory");      \
    __builtin_amdgcn_s_barrier();                              \
    __builtin_amdgcn_sched_barrier(0);                         \
    short8 af[8], bfr[4];                                      \
    _Pragma("unroll")                                          \
    for (int i = 0; i < 8; i++)                                \
      af[i] = *(const short8*)(Lb + aoff[i]);                  \
    _Pragma("unroll")                                          \
    for (int j = 0; j < 4; j++)                                \
      bfr[j] = *(const short8*)(Lb + boff[j]);                 \
    __builtin_amdgcn_s_setprio(1);                             \
    _Pragma("unroll")                                          \
    for (int i = 0; i < 8; i++)                                \
      _Pragma("unroll")                                        \
      for (int j = 0; j < 4; j++)                              \
        acc[i][j] = MFMA16(af[i], bfr[j], acc[i][j]);          \
    __builtin_amdgcn_s_setprio(0);                             \
    asm volatile("s_waitcnt lgkmcnt(0)" ::: "memory");         \
    __builtin_amdgcn_sched_barrier(0);                         \
    __builtin_amdgcn_s_barrier();                              \
  } while (0)

  // prologue: prefetch K-step 0 into buf0
  SSTAGE(0, 0);
  for (int t = 0; t < 23; ++t) {  // NS = 768/32 = 24 k-steps
    SSTAGE((t + 1) & 1, (t + 1) * 32);
    SPHASE(t & 1, "4");
  }
  SPHASE(1, "0");  // t = 23: no stage; drain so epilogue can reuse smem
#undef SSTAGE
#undef SPHASE

  // epilogue: exp + causal mask + row-sum atomics + pack to 128^2 P subtiles.
  // Two rounds over m-halves; each round packs 128x256 into swizzled LDS
  // (64 KB, reusing the staging buffers), then all 512 threads store.
#pragma unroll
  for (int h = 0; h < 2; h++) {
    if (myh == h) {
#pragma unroll
      for (int i = 0; i < 8; i++) {
        float rs[4];
#pragma unroll
        for (int r = 0; r < 4; r++) rs[r] = 0.0f;
#pragma unroll
        for (int j = 0; j < 4; j++) {
          const int col = wn + j * 16 + ln;  // 0..255 within tile
          const int gcol = n0 + col;
#pragma unroll
          for (int r = 0; r < 4; r++) {
            const int row = i * 16 + quad * 4 + r;  // 0..127 within half
            const int grow = m0 + h * 128 + row;
            float p = 0.0f;
            if (gcol <= grow) p = __expf(acc[i][j][r] * scale);
            const ushort pk = f2bf(p);
            smem[row * 256 + (col ^ ((row & 7) << 3))] = pk;
            rs[r] += bf2f(pk);
          }
        }
#pragma unroll
        for (int r = 0; r < 4; r++) {
          float s = rs[r];
          s += __shfl_xor(s, 1);
          s += __shfl_xor(s, 2);
          s += __shfl_xor(s, 4);
          s += __shfl_xor(s, 8);
          if (ln == 0)
            atomicAdd(ls + b * SEQ + m0 + h * 128 + i * 16 + quad * 4 + r, s);
        }
      }
    }
    __syncthreads();
    const int mtr = 2 * mt + h;  // 128-granularity tile row
    ushort* pt0 = pb + ((size_t)(b * 528 + mtr * (mtr + 1) / 2 + 2 * nt) << 14);
    ushort* pt1 = pt0 + (1 << 14);
    const bool st1 = (2 * nt + 1) <= mtr;  // right 128-subtile exists?
#pragma unroll
    for (int p = 0; p < 8; p++) {
      const int tt = p * 512 + tid;  // 0..4095 16B-slots
      const int row = tt >> 5;
      const int cs = tt & 31;
      ushort8 v = *(const ushort8*)&smem[row * 256 + ((cs * 8) ^ ((row & 7) << 3))];
      if (cs < 16) {
        *(ushort8*)(pt0 + row * 128 + cs * 8) = v;
      } else if (st1) {
        *(ushort8*)(pt1 + row * 128 + (cs - 16) * 8) = v;
      }
    }
    __syncthreads();
  }
}

// ---------- kernel 3: O = P_hat @ V, divide by l (BK=64, serpentine) ----------
__global__ __launch_bounds__(256, 4)
void attn_pv(const ushort* __restrict__ pb, const ushort* __restrict__ vt,
             const float* __restrict__ ls, float* __restrict__ out) {
  __shared__ ushort smem[16384];
  ushort* As = smem;
  ushort* Bs = smem + 8192;

  // serpentine rank -> (mt desc, et, b): balances per-CU work at 3 blocks/CU
  int idx = blockIdx.x;
  int chunk = idx >> 8, pos = idx & 255;
  if (chunk & 1) pos = 255 - pos;
  const int r_ = (chunk << 8) + pos;
  const int mt = 31 - r_ / 24;
  const int rem = r_ % 24;
  const int b = rem & 3;
  const int et = rem >> 2;
  const int m0 = mt * 128, e0 = et * 128;

  const int tid = threadIdx.x;
  const int w = tid >> 6, lane = tid & 63, ln = lane & 15, quad = lane >> 4;
  const int wm = (w >> 1) * 64, wn = (w & 1) * 64;
  const size_t vtbase = (size_t)b * DIM * SEQ;
  const ushort* ptiles = pb + ((size_t)(b * 528 + mt * (mt + 1) / 2) << 14);

  const int c0 = w * 128 + lane;
  const int c1 = c0 + 64;
  const int R0 = c0 >> 2, kl0 = (c0 & 3) ^ ((R0 >> 1) & 3);
  const int R1 = c1 >> 2, kl1 = (c1 & 3) ^ ((R1 >> 1) & 3);
  const ushort* ag0 = ptiles + R0 * 128 + kl0 * 8;
  const ushort* ag1 = ptiles + R1 * 128 + kl1 * 8;
  const ushort* bg0 = vt + vtbase + (size_t)(e0 + R0) * SEQ + kl0 * 8;
  const ushort* bg1 = vt + vtbase + (size_t)(e0 + R1) * SEQ + kl1 * 8;
  ushort* al0 = As + (size_t)(w * 128) * 8;
  ushort* al1 = As + (size_t)(w * 128 + 64) * 8;
  ushort* bl0 = Bs + (size_t)(w * 128) * 8;
  ushort* bl1 = Bs + (size_t)(w * 128 + 64) * 8;

  const int sw = quad ^ ((ln >> 1) & 3);
  int aoff[4], boff[4];
#pragma unroll
  for (int i = 0; i < 4; i++) aoff[i] = ((wm + i * 16 + ln) * 4 + sw) * 8;
#pragma unroll
  for (int i = 0; i < 4; i++) boff[i] = ((wn + i * 16 + ln) * 4 + sw) * 8;

  fx4 acc[4][4];
#pragma unroll
  for (int i = 0; i < 4; i++)
#pragma unroll
    for (int j = 0; j < 4; j++) acc[i][j] = (fx4)0.0f;

  const int nk = (mt + 1) * 2;  // 64-wide k-steps
  for (int ks = 0; ks < nk; ks++) {
    const int ntile = ks >> 1;
    const int kin = (ks & 1) * 64;
    const size_t atile = (size_t)ntile * 16384 + kin;
    const int kglob = ntile * 128 + kin;
    gload_lds16(ag0 + atile, al0);
    gload_lds16(ag1 + atile, al1);
    gload_lds16(ag0 + atile + 32, al0 + 4096);
    gload_lds16(ag1 + atile + 32, al1 + 4096);
    gload_lds16(bg0 + kglob, bl0);
    gload_lds16(bg1 + kglob, bl1);
    gload_lds16(bg0 + kglob + 32, bl0 + 4096);
    gload_lds16(bg1 + kglob + 32, bl1 + 4096);
    __syncthreads();
#pragma unroll
    for (int h = 0; h < 2; h++) {
      const int hb = h * 4096;
      short8 af[4], bf[4];
#pragma unroll
      for (int i = 0; i < 4; i++) af[i] = *(const short8*)(As + hb + aoff[i]);
#pragma unroll
      for (int i = 0; i < 4; i++) bf[i] = *(const short8*)(Bs + hb + boff[i]);
#pragma unroll
      for (int i = 0; i < 4; i++)
#pragma unroll
        for (int j = 0; j < 4; j++)
          acc[i][j] = MFMA16(af[i], bf[j], acc[i][j]);
    }
    __syncthreads();
  }

#pragma unroll
  for (int i = 0; i < 4; i++)
#pragma unroll
    for (int r = 0; r < 4; r++) {
      const int row = m0 + wm + i * 16 + quad * 4 + r;
      const float linv = 1.0f / ls[b * SEQ + row];
      float* orow = out + ((size_t)(b * SEQ + row)) * DIM + e0 + wn + ln;
#pragma unroll
      for (int j = 0; j < 4; j++) orow[j * 16] = acc[i][j][r] * linv;
    }
}

extern "C" void kernel_launch(void* const* d_in, const int* in_sizes, int n_in,
                              void* d_out, int out_size, void* d_ws, size_t ws_size,
                              hipStream_t stream) {
  const float* x = (const float*)d_in[0];
  const float* wq = (const float*)d_in[1];
  const float* wk = (const float*)d_in[2];
  const float* wv = (const float*)d_in[3];
  float* out = (float*)d_out;

  ushort* qb = (ushort*)d_ws;
  ushort* kb = qb + 12582912;
  ushort* vt = kb + 12582912;
  ushort* xb = vt + 12582912;
  ushort* wb = xb + 12582912;
  ushort* pb = xb;  // alias: xb/wb dead after qkv_proj
  float* ls = (float*)((ushort*)d_ws + 72351744);

  cvt_all<<<7008, 256, 0, stream>>>(x, wq, wk, wv, xb, wb, ls);
  qkv_proj<<<dim3(128, 18), 256, 0, stream>>>(xb, wb, qb, kb, vt);
  attn_scores<<<dim3(544), 512, 0, stream>>>(qb, kb, pb, ls);
  attn_pv<<<768, 256, 0, stream>>>(pb, vt, ls, out);
}

// Round 3
// 388.886 us; speedup vs baseline: 2.4999x; 2.4999x over previous
//
#include <hip/hip_runtime.h>
#include <stdint.h>

// SelfAttention: B=4, S=4096, D=768, causal, fp32 in/out, bf16 MFMA compute.
// cvt -> qkv GEMM (128x128, 2-barrier) -> scores GEMM (256x256 tile, 512 thr,
// DOUBLE-buffered BK=32 pipeline, counted vmcnt, 64KB LDS -> 2 blocks/CU,
// launch_bounds(512,2): DO NOT raise to (512,4) -- forces VGPR 120->64 and
// spills acc to scratch (2.5 GB traffic, 717us; round-2 post-mortem) ->
// exp epilogue, packed causal P tiles -> PV GEMM (/l epilogue).
// ws layout (bf16 elements):
//   qb  12582912 @ 0
//   kb  12582912 @ 12582912
//   vt  12582912 @ 25165824   [b][e][s] (V transposed)
//   xb  12582912 @ 37748736   (dead after qkv_proj)
//   wb   1769472 @ 50331648   (dead after qkv_proj)
//   pb  34603008 @ 37748736   ALIAS over xb/wb: packed causal P tiles,
//                             tile (b, mt, nt<=mt) at slot b*528+mt(mt+1)/2+nt
//   ls  16384 fp32 @ elem 72351744
#define SEQ 4096
#define DIM 768

typedef __attribute__((ext_vector_type(8))) short short8;
typedef __attribute__((ext_vector_type(8))) unsigned short ushort8;
typedef __attribute__((ext_vector_type(4))) unsigned short ushort4v;
typedef __attribute__((ext_vector_type(4))) float fx4;
typedef unsigned short ushort;

#define MFMA16(a, b, c) __builtin_amdgcn_mfma_f32_16x16x32_bf16((a), (b), (c), 0, 0, 0)

__device__ __forceinline__ ushort f2bf(float f) {
  union { float f; unsigned int u; } v; v.f = f;
  return (ushort)((v.u + 0x7fffu + ((v.u >> 16) & 1u)) >> 16);
}
__device__ __forceinline__ float bf2f(ushort u) {
  union { unsigned int u; float f; } v; v.u = ((unsigned int)u) << 16;
  return v.f;
}
__device__ __forceinline__ void gload_lds16(const ushort* g, ushort* l) {
  __builtin_amdgcn_global_load_lds(
      (const __attribute__((address_space(1))) void*)g,
      (__attribute__((address_space(3))) void*)l, 16, 0, 0);
}

// ---------- kernel 0: fused fp32->bf16 casts + ls zero ----------
__global__ void cvt_all(const float* __restrict__ x, const float* __restrict__ wq,
                        const float* __restrict__ wk, const float* __restrict__ wv,
                        ushort* __restrict__ xb, ushort* __restrict__ wb,
                        float* __restrict__ ls) {
  const int bid = blockIdx.x;
  if (bid < 6144) {
    if (bid < 64) ls[bid * 256 + threadIdx.x] = 0.0f;
    const int i = (bid * 256 + threadIdx.x) * 8;
    fx4 a = *(const fx4*)(x + i);
    fx4 b = *(const fx4*)(x + i + 4);
    ushort8 o;
#pragma unroll
    for (int c = 0; c < 4; c++) { o[c] = f2bf(a[c]); o[c + 4] = f2bf(b[c]); }
    *(ushort8*)(xb + i) = o;
  } else {
    const int i = ((bid - 6144) * 256 + threadIdx.x) * 8;
    const int which = i / (DIM * DIM);
    const int off = i - which * (DIM * DIM);
    const float* src = (which == 0) ? wq : (which == 1) ? wk : wv;
    fx4 a = *(const fx4*)(src + off);
    fx4 b = *(const fx4*)(src + off + 4);
    ushort8 o;
#pragma unroll
    for (int c = 0; c < 4; c++) { o[c] = f2bf(a[c]); o[c + 4] = f2bf(b[c]); }
    *(ushort8*)(wb + i) = o;
  }
}

// ---------- kernel 1: QKV projection (128x128 tile, BK=64) ----------
__global__ __launch_bounds__(256, 4)
void qkv_proj(const ushort* __restrict__ xb, const ushort* __restrict__ wb,
              ushort* __restrict__ qb, ushort* __restrict__ kb,
              ushort* __restrict__ vt) {
  __shared__ ushort smem[17408];  // k-loop: As[8192]|Bs[8192]; epilogue 128x136
  ushort* As = smem;
  ushort* Bs = smem + 8192;

  const int mb = blockIdx.x, nb = blockIdx.y;
  const int which = nb / 6;
  const int e0 = (nb % 6) * 128;
  const int m0 = mb * 128;
  const int tid = threadIdx.x;
  const int w = tid >> 6, lane = tid & 63, ln = lane & 15, quad = lane >> 4;
  const int wm = (w >> 1) * 64, wn = (w & 1) * 64;

  const ushort* W = wb + (size_t)which * (DIM * DIM);

  const int c0 = w * 128 + lane;
  const int c1 = c0 + 64;
  const int R0 = c0 >> 2, kl0 = (c0 & 3) ^ ((R0 >> 1) & 3);
  const int R1 = c1 >> 2, kl1 = (c1 & 3) ^ ((R1 >> 1) & 3);
  const ushort* ag0 = xb + (size_t)(m0 + R0) * DIM + kl0 * 8;
  const ushort* ag1 = xb + (size_t)(m0 + R1) * DIM + kl1 * 8;
  const ushort* bg0 = W + (size_t)(e0 + R0) * DIM + kl0 * 8;
  const ushort* bg1 = W + (size_t)(e0 + R1) * DIM + kl1 * 8;
  ushort* al0 = As + (size_t)(w * 128) * 8;
  ushort* al1 = As + (size_t)(w * 128 + 64) * 8;
  ushort* bl0 = Bs + (size_t)(w * 128) * 8;
  ushort* bl1 = Bs + (size_t)(w * 128 + 64) * 8;

  const int sw = quad ^ ((ln >> 1) & 3);
  int aoff[4], boff[4];
#pragma unroll
  for (int i = 0; i < 4; i++) aoff[i] = ((wm + i * 16 + ln) * 4 + sw) * 8;
#pragma unroll
  for (int i = 0; i < 4; i++) boff[i] = ((wn + i * 16 + ln) * 4 + sw) * 8;

  fx4 acc[4][4];
#pragma unroll
  for (int i = 0; i < 4; i++)
#pragma unroll
    for (int j = 0; j < 4; j++) acc[i][j] = (fx4)0.0f;

  for (int kk = 0; kk < DIM; kk += 64) {
    gload_lds16(ag0 + kk, al0);
    gload_lds16(ag1 + kk, al1);
    gload_lds16(ag0 + kk + 32, al0 + 4096);
    gload_lds16(ag1 + kk + 32, al1 + 4096);
    gload_lds16(bg0 + kk, bl0);
    gload_lds16(bg1 + kk, bl1);
    gload_lds16(bg0 + kk + 32, bl0 + 4096);
    gload_lds16(bg1 + kk + 32, bl1 + 4096);
    __syncthreads();
#pragma unroll
    for (int h = 0; h < 2; h++) {
      const int hb = h * 4096;
      short8 af[4], bf[4];
#pragma unroll
      for (int i = 0; i < 4; i++) af[i] = *(const short8*)(As + hb + aoff[i]);
#pragma unroll
      for (int i = 0; i < 4; i++) bf[i] = *(const short8*)(Bs + hb + boff[i]);
#pragma unroll
      for (int i = 0; i < 4; i++)
#pragma unroll
        for (int j = 0; j < 4; j++)
          acc[i][j] = MFMA16(af[i], bf[j], acc[i][j]);
    }
    __syncthreads();
  }

  if (which == 2) {
#pragma unroll
    for (int i = 0; i < 4; i++)
#pragma unroll
      for (int j = 0; j < 4; j++) {
        const int s = m0 + wm + i * 16 + quad * 4;
        const int e = e0 + wn + j * 16 + ln;
        const int bb = s >> 12, si = s & 4095;
        ushort4v p;
#pragma unroll
        for (int r = 0; r < 4; r++) p[r] = f2bf(acc[i][j][r]);
        *(ushort4v*)(vt + ((size_t)bb * DIM + e) * SEQ + si) = p;
      }
  } else {
#pragma unroll
    for (int i = 0; i < 4; i++)
#pragma unroll
      for (int j = 0; j < 4; j++)
#pragma unroll
        for (int r = 0; r < 4; r++)
          smem[(wm + i * 16 + quad * 4 + r) * 136 + wn + j * 16 + ln] =
              f2bf(acc[i][j][r]);
    __syncthreads();
    ushort* dst = (which == 0) ? qb : kb;
#pragma unroll
    for (int p = 0; p < 8; p++) {
      const int tt = p * 256 + tid;
      const int row = tt >> 4, col = (tt & 15) * 8;
      ushort8 v = *(const ushort8*)&smem[row * 136 + col];
      *(ushort8*)(dst + (size_t)(m0 + row) * DIM + e0 + col) = v;
    }
  }
}

// ---------- kernel 2: scores GEMM, 256x256 tile, double-buffered BK=32 -----
// 512 thr = 8 waves (2M x 4N); per-wave 128x64 out, acc[8][4].
// LDS: 2 buffers x 32KB -> 64KB total -> 2 blocks/CU (4 waves/SIMD): barrier
// stalls in one block are covered by the co-resident block (m114 mechanism).
// launch_bounds(512,2): VGPR ~120 fits 4 waves/SIMD naturally; (512,4) caps
// allocator at 64 and spills acc (round-2: 2.5GB scratch traffic, 717us).
// Pipeline: stage buf[t+1] -> vmcnt(4) (cur buf's loads done, next's 4 stay
// in flight across both barriers) -> barrier -> 12x ds_read_b128 + 32 MFMA
// (compiler interleaves, counted lgkm) -> lgkmcnt(0) -> barrier.
// Last iter: no stage, vmcnt(0) so the epilogue's smem reuse is race-free.
__global__ __launch_bounds__(512, 2)
void attn_scores(const ushort* __restrict__ qb, const ushort* __restrict__ kb,
                 ushort* __restrict__ pb, float* __restrict__ ls) {
  __shared__ ushort smem[32768];  // 64 KiB: 2 x 16384-ushort buffers

  // XCD-aware bijective swizzle: 544 blocks = 8 XCDs x 68
  const int r0 = blockIdx.x;
  const int wg = (r0 & 7) * 68 + (r0 >> 3);
  const int b = wg / 136;
  const int pr = wg - b * 136;
  int mt = (int)(0.5f * (sqrtf(8.0f * pr + 1.0f) - 1.0f));
  while ((mt + 1) * (mt + 2) / 2 <= pr) ++mt;
  while (mt * (mt + 1) / 2 > pr) --mt;
  const int nt = pr - mt * (mt + 1) / 2;
  const int m0 = mt * 256, n0 = nt * 256;

  const int tid = threadIdx.x;
  const int w = tid >> 6, lane = tid & 63, ln = lane & 15, quad = lane >> 4;
  const int wn = (w & 3) * 64;
  const size_t qkbase = (size_t)b * SEQ * DIM;
  const float scale = 0.03608439182435161f;  // 1/sqrt(768)

  // staging: 512 threads cover one 128x32 chunk per gload (slot t: row t>>2,
  // k-group kl = (t&3)^((row>>1)&3); LDS dest linear, source pre-swizzled)
  const int R = tid >> 2;
  const int kl = (tid & 3) ^ ((R >> 1) & 3);
  const ushort* ag0 = qb + qkbase + (size_t)(m0 + R) * DIM + kl * 8;
  const ushort* ag1 = qb + qkbase + (size_t)(m0 + 128 + R) * DIM + kl * 8;
  const ushort* bg0 = kb + qkbase + (size_t)(n0 + R) * DIM + kl * 8;
  const ushort* bg1 = kb + qkbase + (size_t)(n0 + 128 + R) * DIM + kl * 8;
  const int ldsw = w * 512;  // this wave's 1KB slice within a chunk (ushorts)

  // fragment read offsets (ushort units, within one 32KB buffer)
  const int sw = quad ^ ((ln >> 1) & 3);
  const int myh = w >> 2;  // wave's m-half
  int aoff[8], boff[4];
#pragma unroll
  for (int i = 0; i < 8; i++)
    aoff[i] = myh * 4096 + (i * 16 + ln) * 32 + sw * 8;
#pragma unroll
  for (int j = 0; j < 4; j++)
    boff[j] = 8192 + (wn >> 7) * 4096 + ((wn & 127) + j * 16 + ln) * 32 + sw * 8;

  fx4 acc[8][4];
#pragma unroll
  for (int i = 0; i < 8; i++)
#pragma unroll
    for (int j = 0; j < 4; j++) acc[i][j] = (fx4)0.0f;

#define SSTAGE(BUF, KO) do {                                   \
    ushort* Lb = smem + (BUF) * 16384;                         \
    gload_lds16(ag0 + (KO), Lb + ldsw);                        \
    gload_lds16(ag1 + (KO), Lb + 4096 + ldsw);                 \
    gload_lds16(bg0 + (KO), Lb + 8192 + ldsw);                 \
    gload_lds16(bg1 + (KO), Lb + 12288 + ldsw);                \
  } while (0)

#define SPHASE(BUF, VM) do {                                   \
    const ushort* Lb = smem + (BUF) * 16384;                   \
    asm volatile("s_waitcnt vmcnt(" VM ")" ::: "memory");      \
    __builtin_amdgcn_s_barrier();                              \
    __builtin_amdgcn_sched_barrier(0);                         \
    short8 af[8], bfr[4];                                      \
    _Pragma("unroll")                                          \
    for (int i = 0; i < 8; i++)                                \
      af[i] = *(const short8*)(Lb + aoff[i]);                  \
    _Pragma("unroll")                                          \
    for (int j = 0; j < 4; j++)                                \
      bfr[j] = *(const short8*)(Lb + boff[j]);                 \
    __builtin_amdgcn_s_setprio(1);                             \
    _Pragma("unroll")                                          \
    for (int i = 0; i < 8; i++)                                \
      _Pragma("unroll")                                        \
      for (int j = 0; j < 4; j++)                              \
        acc[i][j] = MFMA16(af[i], bfr[j], acc[i][j]);          \
    __builtin_amdgcn_s_setprio(0);                             \
    asm volatile("s_waitcnt lgkmcnt(0)" ::: "memory");         \
    __builtin_amdgcn_sched_barrier(0);                         \
    __builtin_amdgcn_s_barrier();                              \
  } while (0)

  // prologue: prefetch K-step 0 into buf0
  SSTAGE(0, 0);
  for (int t = 0; t < 23; ++t) {  // NS = 768/32 = 24 k-steps
    SSTAGE((t + 1) & 1, (t + 1) * 32);
    SPHASE(t & 1, "4");
  }
  SPHASE(1, "0");  // t = 23: no stage; drain so epilogue can reuse smem
#undef SSTAGE
#undef SPHASE

  // epilogue: exp + causal mask + row-sum atomics + pack to 128^2 P subtiles.
  // Two rounds over m-halves; each round packs 128x256 into swizzled LDS
  // (64 KB, reusing the staging buffers), then all 512 threads store.
#pragma unroll
  for (int h = 0; h < 2; h++) {
    if (myh == h) {
#pragma unroll
      for (int i = 0; i < 8; i++) {
        float rs[4];
#pragma unroll
        for (int r = 0; r < 4; r++) rs[r] = 0.0f;
#pragma unroll
        for (int j = 0; j < 4; j++) {
          const int col = wn + j * 16 + ln;  // 0..255 within tile
          const int gcol = n0 + col;
#pragma unroll
          for (int r = 0; r < 4; r++) {
            const int row = i * 16 + quad * 4 + r;  // 0..127 within half
            const int grow = m0 + h * 128 + row;
            float p = 0.0f;
            if (gcol <= grow) p = __expf(acc[i][j][r] * scale);
            const ushort pk = f2bf(p);
            smem[row * 256 + (col ^ ((row & 7) << 3))] = pk;
            rs[r] += bf2f(pk);
          }
        }
#pragma unroll
        for (int r = 0; r < 4; r++) {
          float s = rs[r];
          s += __shfl_xor(s, 1);
          s += __shfl_xor(s, 2);
          s += __shfl_xor(s, 4);
          s += __shfl_xor(s, 8);
          if (ln == 0)
            atomicAdd(ls + b * SEQ + m0 + h * 128 + i * 16 + quad * 4 + r, s);
        }
      }
    }
    __syncthreads();
    const int mtr = 2 * mt + h;  // 128-granularity tile row
    ushort* pt0 = pb + ((size_t)(b * 528 + mtr * (mtr + 1) / 2 + 2 * nt) << 14);
    ushort* pt1 = pt0 + (1 << 14);
    const bool st1 = (2 * nt + 1) <= mtr;  // right 128-subtile exists?
#pragma unroll
    for (int p = 0; p < 8; p++) {
      const int tt = p * 512 + tid;  // 0..4095 16B-slots
      const int row = tt >> 5;
      const int cs = tt & 31;
      ushort8 v = *(const ushort8*)&smem[row * 256 + ((cs * 8) ^ ((row & 7) << 3))];
      if (cs < 16) {
        *(ushort8*)(pt0 + row * 128 + cs * 8) = v;
      } else if (st1) {
        *(ushort8*)(pt1 + row * 128 + (cs - 16) * 8) = v;
      }
    }
    __syncthreads();
  }
}

// ---------- kernel 3: O = P_hat @ V, divide by l (BK=64, serpentine) ----------
__global__ __launch_bounds__(256, 4)
void attn_pv(const ushort* __restrict__ pb, const ushort* __restrict__ vt,
             const float* __restrict__ ls, float* __restrict__ out) {
  __shared__ ushort smem[16384];
  ushort* As = smem;
  ushort* Bs = smem + 8192;

  // serpentine rank -> (mt desc, et, b): balances per-CU work at 3 blocks/CU
  int idx = blockIdx.x;
  int chunk = idx >> 8, pos = idx & 255;
  if (chunk & 1) pos = 255 - pos;
  const int r_ = (chunk << 8) + pos;
  const int mt = 31 - r_ / 24;
  const int rem = r_ % 24;
  const int b = rem & 3;
  const int et = rem >> 2;
  const int m0 = mt * 128, e0 = et * 128;

  const int tid = threadIdx.x;
  const int w = tid >> 6, lane = tid & 63, ln = lane & 15, quad = lane >> 4;
  const int wm = (w >> 1) * 64, wn = (w & 1) * 64;
  const size_t vtbase = (size_t)b * DIM * SEQ;
  const ushort* ptiles = pb + ((size_t)(b * 528 + mt * (mt + 1) / 2) << 14);

  const int c0 = w * 128 + lane;
  const int c1 = c0 + 64;
  const int R0 = c0 >> 2, kl0 = (c0 & 3) ^ ((R0 >> 1) & 3);
  const int R1 = c1 >> 2, kl1 = (c1 & 3) ^ ((R1 >> 1) & 3);
  const ushort* ag0 = ptiles + R0 * 128 + kl0 * 8;
  const ushort* ag1 = ptiles + R1 * 128 + kl1 * 8;
  const ushort* bg0 = vt + vtbase + (size_t)(e0 + R0) * SEQ + kl0 * 8;
  const ushort* bg1 = vt + vtbase + (size_t)(e0 + R1) * SEQ + kl1 * 8;
  ushort* al0 = As + (size_t)(w * 128) * 8;
  ushort* al1 = As + (size_t)(w * 128 + 64) * 8;
  ushort* bl0 = Bs + (size_t)(w * 128) * 8;
  ushort* bl1 = Bs + (size_t)(w * 128 + 64) * 8;

  const int sw = quad ^ ((ln >> 1) & 3);
  int aoff[4], boff[4];
#pragma unroll
  for (int i = 0; i < 4; i++) aoff[i] = ((wm + i * 16 + ln) * 4 + sw) * 8;
#pragma unroll
  for (int i = 0; i < 4; i++) boff[i] = ((wn + i * 16 + ln) * 4 + sw) * 8;

  fx4 acc[4][4];
#pragma unroll
  for (int i = 0; i < 4; i++)
#pragma unroll
    for (int j = 0; j < 4; j++) acc[i][j] = (fx4)0.0f;

  const int nk = (mt + 1) * 2;  // 64-wide k-steps
  for (int ks = 0; ks < nk; ks++) {
    const int ntile = ks >> 1;
    const int kin = (ks & 1) * 64;
    const size_t atile = (size_t)ntile * 16384 + kin;
    const int kglob = ntile * 128 + kin;
    gload_lds16(ag0 + atile, al0);
    gload_lds16(ag1 + atile, al1);
    gload_lds16(ag0 + atile + 32, al0 + 4096);
    gload_lds16(ag1 + atile + 32, al1 + 4096);
    gload_lds16(bg0 + kglob, bl0);
    gload_lds16(bg1 + kglob, bl1);
    gload_lds16(bg0 + kglob + 32, bl0 + 4096);
    gload_lds16(bg1 + kglob + 32, bl1 + 4096);
    __syncthreads();
#pragma unroll
    for (int h = 0; h < 2; h++) {
      const int hb = h * 4096;
      short8 af[4], bf[4];
#pragma unroll
      for (int i = 0; i < 4; i++) af[i] = *(const short8*)(As + hb + aoff[i]);
#pragma unroll
      for (int i = 0; i < 4; i++) bf[i] = *(const short8*)(Bs + hb + boff[i]);
#pragma unroll
      for (int i = 0; i < 4; i++)
#pragma unroll
        for (int j = 0; j < 4; j++)
          acc[i][j] = MFMA16(af[i], bf[j], acc[i][j]);
    }
    __syncthreads();
  }

#pragma unroll
  for (int i = 0; i < 4; i++)
#pragma unroll
    for (int r = 0; r < 4; r++) {
      const int row = m0 + wm + i * 16 + quad * 4 + r;
      const float linv = 1.0f / ls[b * SEQ + row];
      float* orow = out + ((size_t)(b * SEQ + row)) * DIM + e0 + wn + ln;
#pragma unroll
      for (int j = 0; j < 4; j++) orow[j * 16] = acc[i][j][r] * linv;
    }
}

extern "C" void kernel_launch(void* const* d_in, const int* in_sizes, int n_in,
                              void* d_out, int out_size, void* d_ws, size_t ws_size,
                              hipStream_t stream) {
  const float* x = (const float*)d_in[0];
  const float* wq = (const float*)d_in[1];
  const float* wk = (const float*)d_in[2];
  const float* wv = (const float*)d_in[3];
  float* out = (float*)d_out;

  ushort* qb = (ushort*)d_ws;
  ushort* kb = qb + 12582912;
  ushort* vt = kb + 12582912;
  ushort* xb = vt + 12582912;
  ushort* wb = xb + 12582912;
  ushort* pb = xb;  // alias: xb/wb dead after qkv_proj
  float* ls = (float*)((ushort*)d_ws + 72351744);

  cvt_all<<<7008, 256, 0, stream>>>(x, wq, wk, wv, xb, wb, ls);
  qkv_proj<<<dim3(128, 18), 256, 0, stream>>>(xb, wb, qb, kb, vt);
  attn_scores<<<dim3(544), 512, 0, stream>>>(qb, kb, pb, ls);
  attn_pv<<<768, 256, 0, stream>>>(pb, vt, ls, out);
}

// Round 4
// 373.391 us; speedup vs baseline: 2.6037x; 1.0415x over previous
//
#include <hip/hip_runtime.h>
#include <stdint.h>

// SelfAttention: B=4, S=4096, D=768, causal, fp32 in/out, bf16 MFMA compute.
// cvt -> qkv GEMM (128x128, 2-barrier) -> scores GEMM (256x256 tile, 512 thr,
// m201-style 8-PHASE schedule: BK=64, 2 K-tile LDS slots (128KB), per-phase
// {async ds_reads + 1 chunk-pair stage -> barrier -> lgkm0 -> 16 MFMA ->
// barrier}, vmcnt(6) only at phases 4/8) -> PV GEMM (/l epilogue).
// Round-2 lesson: acc[8][4]=128 regs + ~120 VGPR = ~250/512 -> 2 waves/SIMD
// structurally; launch_bounds(512,2) (NOT 4: spills acc, 2.5GB scratch).
// ws layout (bf16 elements):
//   qb  12582912 @ 0
//   kb  12582912 @ 12582912
//   vt  12582912 @ 25165824   [b][e][s] (V transposed)
//   xb  12582912 @ 37748736   (dead after qkv_proj)
//   wb   1769472 @ 50331648   (dead after qkv_proj)
//   pb  34603008 @ 37748736   ALIAS over xb/wb: packed causal P tiles,
//                             tile (b, mt, nt<=mt) at slot b*528+mt(mt+1)/2+nt
//   ls  16384 fp32 @ elem 72351744
#define SEQ 4096
#define DIM 768

typedef __attribute__((ext_vector_type(8))) short short8;
typedef __attribute__((ext_vector_type(8))) unsigned short ushort8;
typedef __attribute__((ext_vector_type(4))) unsigned short ushort4v;
typedef __attribute__((ext_vector_type(4))) float fx4;
typedef unsigned short ushort;

#define MFMA16(a, b, c) __builtin_amdgcn_mfma_f32_16x16x32_bf16((a), (b), (c), 0, 0, 0)

__device__ __forceinline__ ushort f2bf(float f) {
  union { float f; unsigned int u; } v; v.f = f;
  return (ushort)((v.u + 0x7fffu + ((v.u >> 16) & 1u)) >> 16);
}
__device__ __forceinline__ float bf2f(ushort u) {
  union { unsigned int u; float f; } v; v.u = ((unsigned int)u) << 16;
  return v.f;
}
__device__ __forceinline__ void gload_lds16(const ushort* g, ushort* l) {
  __builtin_amdgcn_global_load_lds(
      (const __attribute__((address_space(1))) void*)g,
      (__attribute__((address_space(3))) void*)l, 16, 0, 0);
}

// ---------- kernel 0: fused fp32->bf16 casts + ls zero ----------
__global__ void cvt_all(const float* __restrict__ x, const float* __restrict__ wq,
                        const float* __restrict__ wk, const float* __restrict__ wv,
                        ushort* __restrict__ xb, ushort* __restrict__ wb,
                        float* __restrict__ ls) {
  const int bid = blockIdx.x;
  if (bid < 6144) {
    if (bid < 64) ls[bid * 256 + threadIdx.x] = 0.0f;
    const int i = (bid * 256 + threadIdx.x) * 8;
    fx4 a = *(const fx4*)(x + i);
    fx4 b = *(const fx4*)(x + i + 4);
    ushort8 o;
#pragma unroll
    for (int c = 0; c < 4; c++) { o[c] = f2bf(a[c]); o[c + 4] = f2bf(b[c]); }
    *(ushort8*)(xb + i) = o;
  } else {
    const int i = ((bid - 6144) * 256 + threadIdx.x) * 8;
    const int which = i / (DIM * DIM);
    const int off = i - which * (DIM * DIM);
    const float* src = (which == 0) ? wq : (which == 1) ? wk : wv;
    fx4 a = *(const fx4*)(src + off);
    fx4 b = *(const fx4*)(src + off + 4);
    ushort8 o;
#pragma unroll
    for (int c = 0; c < 4; c++) { o[c] = f2bf(a[c]); o[c + 4] = f2bf(b[c]); }
    *(ushort8*)(wb + i) = o;
  }
}

// ---------- kernel 1: QKV projection (128x128 tile, BK=64) ----------
__global__ __launch_bounds__(256, 4)
void qkv_proj(const ushort* __restrict__ xb, const ushort* __restrict__ wb,
              ushort* __restrict__ qb, ushort* __restrict__ kb,
              ushort* __restrict__ vt) {
  __shared__ ushort smem[17408];  // k-loop: As[8192]|Bs[8192]; epilogue 128x136
  ushort* As = smem;
  ushort* Bs = smem + 8192;

  const int mb = blockIdx.x, nb = blockIdx.y;
  const int which = nb / 6;
  const int e0 = (nb % 6) * 128;
  const int m0 = mb * 128;
  const int tid = threadIdx.x;
  const int w = tid >> 6, lane = tid & 63, ln = lane & 15, quad = lane >> 4;
  const int wm = (w >> 1) * 64, wn = (w & 1) * 64;

  const ushort* W = wb + (size_t)which * (DIM * DIM);

  const int c0 = w * 128 + lane;
  const int c1 = c0 + 64;
  const int R0 = c0 >> 2, kl0 = (c0 & 3) ^ ((R0 >> 1) & 3);
  const int R1 = c1 >> 2, kl1 = (c1 & 3) ^ ((R1 >> 1) & 3);
  const ushort* ag0 = xb + (size_t)(m0 + R0) * DIM + kl0 * 8;
  const ushort* ag1 = xb + (size_t)(m0 + R1) * DIM + kl1 * 8;
  const ushort* bg0 = W + (size_t)(e0 + R0) * DIM + kl0 * 8;
  const ushort* bg1 = W + (size_t)(e0 + R1) * DIM + kl1 * 8;
  ushort* al0 = As + (size_t)(w * 128) * 8;
  ushort* al1 = As + (size_t)(w * 128 + 64) * 8;
  ushort* bl0 = Bs + (size_t)(w * 128) * 8;
  ushort* bl1 = Bs + (size_t)(w * 128 + 64) * 8;

  const int sw = quad ^ ((ln >> 1) & 3);
  int aoff[4], boff[4];
#pragma unroll
  for (int i = 0; i < 4; i++) aoff[i] = ((wm + i * 16 + ln) * 4 + sw) * 8;
#pragma unroll
  for (int i = 0; i < 4; i++) boff[i] = ((wn + i * 16 + ln) * 4 + sw) * 8;

  fx4 acc[4][4];
#pragma unroll
  for (int i = 0; i < 4; i++)
#pragma unroll
    for (int j = 0; j < 4; j++) acc[i][j] = (fx4)0.0f;

  for (int kk = 0; kk < DIM; kk += 64) {
    gload_lds16(ag0 + kk, al0);
    gload_lds16(ag1 + kk, al1);
    gload_lds16(ag0 + kk + 32, al0 + 4096);
    gload_lds16(ag1 + kk + 32, al1 + 4096);
    gload_lds16(bg0 + kk, bl0);
    gload_lds16(bg1 + kk, bl1);
    gload_lds16(bg0 + kk + 32, bl0 + 4096);
    gload_lds16(bg1 + kk + 32, bl1 + 4096);
    __syncthreads();
#pragma unroll
    for (int h = 0; h < 2; h++) {
      const int hb = h * 4096;
      short8 af[4], bf[4];
#pragma unroll
      for (int i = 0; i < 4; i++) af[i] = *(const short8*)(As + hb + aoff[i]);
#pragma unroll
      for (int i = 0; i < 4; i++) bf[i] = *(const short8*)(Bs + hb + boff[i]);
#pragma unroll
      for (int i = 0; i < 4; i++)
#pragma unroll
        for (int j = 0; j < 4; j++)
          acc[i][j] = MFMA16(af[i], bf[j], acc[i][j]);
    }
    __syncthreads();
  }

  if (which == 2) {
#pragma unroll
    for (int i = 0; i < 4; i++)
#pragma unroll
      for (int j = 0; j < 4; j++) {
        const int s = m0 + wm + i * 16 + quad * 4;
        const int e = e0 + wn + j * 16 + ln;
        const int bb = s >> 12, si = s & 4095;
        ushort4v p;
#pragma unroll
        for (int r = 0; r < 4; r++) p[r] = f2bf(acc[i][j][r]);
        *(ushort4v*)(vt + ((size_t)bb * DIM + e) * SEQ + si) = p;
      }
  } else {
#pragma unroll
    for (int i = 0; i < 4; i++)
#pragma unroll
      for (int j = 0; j < 4; j++)
#pragma unroll
        for (int r = 0; r < 4; r++)
          smem[(wm + i * 16 + quad * 4 + r) * 136 + wn + j * 16 + ln] =
              f2bf(acc[i][j][r]);
    __syncthreads();
    ushort* dst = (which == 0) ? qb : kb;
#pragma unroll
    for (int p = 0; p < 8; p++) {
      const int tt = p * 256 + tid;
      const int row = tt >> 4, col = (tt & 15) * 8;
      ushort8 v = *(const ushort8*)&smem[row * 136 + col];
      *(ushort8*)(dst + (size_t)(m0 + row) * DIM + e0 + col) = v;
    }
  }
}

// ---------- kernel 2: scores GEMM, 256x256, m201-style 8-phase, BK=64 ------
// 8 waves (2M x 4N), per-wave 128x64 C = acc[8][4]. LDS 128KB = 2 K-tile
// slots (slot s = K-tile parity), each slot = 8 chunks of 8KB (128 rows x
// 32 k): A(h,kh) then B(h,kh). Per 8-phase iteration: consume K-tiles 2t
// (slot0, ph1-4) and 2t+1 (slot1, ph5-8); each phase stages one chunk-pair
// into the region whose last read was the PREVIOUS phase (race-free: reads
// complete before the barrier that precedes the overwrite). vmcnt(6) at
// ph4/ph8 only (3 chunk-pairs in flight); lgkmcnt(0) after each barrier.
// Phase quadrants: (i-half x k-half), B frags live 2 phases in regs.
// K-order per acc element unchanged -> bitwise-identical numerics.
__global__ __launch_bounds__(512, 2)
void attn_scores(const ushort* __restrict__ qb, const ushort* __restrict__ kb,
                 ushort* __restrict__ pb, float* __restrict__ ls) {
  __shared__ ushort smem[65536];  // 128 KiB

  // XCD-aware bijective swizzle: 544 blocks = 8 XCDs x 68
  const int r0 = blockIdx.x;
  const int wg = (r0 & 7) * 68 + (r0 >> 3);
  const int b = wg / 136;
  const int pr = wg - b * 136;
  int mt = (int)(0.5f * (sqrtf(8.0f * pr + 1.0f) - 1.0f));
  while ((mt + 1) * (mt + 2) / 2 <= pr) ++mt;
  while (mt * (mt + 1) / 2 > pr) --mt;
  const int nt = pr - mt * (mt + 1) / 2;
  const int m0 = mt * 256, n0 = nt * 256;

  const int tid = threadIdx.x;
  const int w = tid >> 6, lane = tid & 63, ln = lane & 15, quad = lane >> 4;
  const int wn = (w & 3) * 64;
  const int mh = w >> 2;        // wave m-half (A chunk select)
  const int nh = (w >> 1) & 1;  // wave n-half (B chunk select)
  const int cbase = (w & 1) * 64;  // col base within B chunk
  const size_t qkbase = (size_t)b * SEQ * DIM;
  const float scale = 0.03608439182435161f;  // 1/sqrt(768)

  // staging: one gload = one 8KB chunk (512 thr x 16B). slot t: row R=t>>2,
  // k-group kl=(t&3)^((R>>1)&3); LDS dest linear, source pre-swizzled.
  const int R = tid >> 2;
  const int kl = (tid & 3) ^ ((R >> 1) & 3);
  const ushort* ag0 = qb + qkbase + (size_t)(m0 + R) * DIM + kl * 8;
  const ushort* ag1 = qb + qkbase + (size_t)(m0 + 128 + R) * DIM + kl * 8;
  const ushort* bg0 = kb + qkbase + (size_t)(n0 + R) * DIM + kl * 8;
  const ushort* bg1 = kb + qkbase + (size_t)(n0 + 128 + R) * DIM + kl * 8;
  const int ldsw = w << 9;  // wave's 1KB slice within a chunk (ushorts)

  // fragment read offsets within a chunk (ushort units)
  const int sw = quad ^ ((ln >> 1) & 3);
  int aro[8], bro[4];
#pragma unroll
  for (int f = 0; f < 8; f++) aro[f] = (f * 16 + ln) * 32 + sw * 8;
#pragma unroll
  for (int j = 0; j < 4; j++) bro[j] = (cbase + j * 16 + ln) * 32 + sw * 8;

  fx4 acc[8][4];
#pragma unroll
  for (int i = 0; i < 8; i++)
#pragma unroll
    for (int j = 0; j < 4; j++) acc[i][j] = (fx4)0.0f;

  short8 af[4], bf[4];

#define A_CH(S, H, KH) (((S) << 15) + (((H) * 2 + (KH)) << 12))
#define B_CH(S, H, KH) (((S) << 15) + 16384 + (((H) * 2 + (KH)) << 12))
#define STG(CH, SRC, GK) gload_lds16((SRC) + (GK), smem + (CH) + ldsw)
#define STGA(S, KH, GK) do { STG(A_CH(S, 0, KH), ag0, GK); \
                             STG(A_CH(S, 1, KH), ag1, GK); } while (0)
#define STGB(S, KH, GK) do { STG(B_CH(S, 0, KH), bg0, GK); \
                             STG(B_CH(S, 1, KH), bg1, GK); } while (0)
#define RDA(S, KH, IH) do { _Pragma("unroll") \
    for (int f = 0; f < 4; f++) \
      af[f] = *(const short8*)(smem + A_CH(S, mh, KH) + aro[(IH) * 4 + f]); \
  } while (0)
#define RDB(S, KH) do { _Pragma("unroll") \
    for (int j = 0; j < 4; j++) \
      bf[j] = *(const short8*)(smem + B_CH(S, nh, KH) + bro[j]); \
  } while (0)
#define VM6() do { asm volatile("s_waitcnt vmcnt(6)" ::: "memory"); } while (0)
#define PHTAIL() do { \
    __builtin_amdgcn_sched_barrier(0); \
    __builtin_amdgcn_s_barrier(); \
    asm volatile("s_waitcnt lgkmcnt(0)" ::: "memory"); \
    __builtin_amdgcn_sched_barrier(0); \
  } while (0)
#define MM(IH) do { _Pragma("unroll") \
    for (int i = 0; i < 4; i++) \
      _Pragma("unroll") \
      for (int j = 0; j < 4; j++) \
        acc[(IH) * 4 + i][j] = MFMA16(af[i], bf[j], acc[(IH) * 4 + i][j]); \
  } while (0)
#define MMWRAP(IH) do { \
    __builtin_amdgcn_s_setprio(1); \
    MM(IH); \
    __builtin_amdgcn_s_setprio(0); \
    __builtin_amdgcn_sched_barrier(0); \
    __builtin_amdgcn_s_barrier(); \
  } while (0)

  // prologue: X(0) full (8 chunks, oldest), Y(1) b_klo,a_klo,b_khi (6)
  STGA(0, 0, 0); STGB(0, 0, 0);
  STGA(0, 1, 32); STGB(0, 1, 32);
  STGB(1, 0, 64); STGA(1, 0, 64);
  STGB(1, 1, 96);
  VM6();
  __builtin_amdgcn_sched_barrier(0);
  __builtin_amdgcn_s_barrier();

  for (int t = 0; t < 5; ++t) {  // steady iters: consume K-tiles 2t, 2t+1
    const int kB = t << 7;
    RDA(0, 0, 0); RDB(0, 0); STGA(1, 1, kB + 96);   PHTAIL(); MMWRAP(0);  // ph1
    RDA(0, 0, 1);            STGB(0, 0, kB + 128);  PHTAIL(); MMWRAP(1);  // ph2
    RDA(0, 1, 0); RDB(0, 1); STGA(0, 0, kB + 128);  PHTAIL(); MMWRAP(0);  // ph3
    RDA(0, 1, 1);            STGB(0, 1, kB + 160);
    VM6();                                          PHTAIL(); MMWRAP(1);  // ph4
    RDA(1, 0, 0); RDB(1, 0); STGA(0, 1, kB + 160);  PHTAIL(); MMWRAP(0);  // ph5
    RDA(1, 0, 1);            STGB(1, 0, kB + 192);  PHTAIL(); MMWRAP(1);  // ph6
    RDA(1, 1, 0); RDB(1, 1); STGA(1, 0, kB + 192);  PHTAIL(); MMWRAP(0);  // ph7
    RDA(1, 1, 1);            STGB(1, 1, kB + 224);
    VM6();                                          PHTAIL(); MMWRAP(1);  // ph8
  }
  // final iter: consume K-tiles 10,11; only Y(11).a_khi still to stage (ph1)
  RDA(0, 0, 0); RDB(0, 0); STGA(1, 1, 736); PHTAIL(); MMWRAP(0);
  RDA(0, 0, 1);                             PHTAIL(); MMWRAP(1);
  RDA(0, 1, 0); RDB(0, 1);                  PHTAIL(); MMWRAP(0);
  RDA(0, 1, 1);
  asm volatile("s_waitcnt vmcnt(0)" ::: "memory");
  PHTAIL(); MMWRAP(1);
  RDA(1, 0, 0); RDB(1, 0);                  PHTAIL(); MMWRAP(0);
  RDA(1, 0, 1);                             PHTAIL(); MMWRAP(1);
  RDA(1, 1, 0); RDB(1, 1);                  PHTAIL(); MMWRAP(0);
  RDA(1, 1, 1);                             PHTAIL(); MMWRAP(1);

#undef A_CH
#undef B_CH
#undef STG
#undef STGA
#undef STGB
#undef RDA
#undef RDB
#undef VM6
#undef PHTAIL
#undef MM
#undef MMWRAP

  // epilogue: exp + causal mask + row-sum atomics + pack to 128^2 P subtiles.
  // Two rounds over m-halves; each round packs 128x256 into swizzled LDS
  // (64 KB = slot0, dead after the K-loop), then all 512 threads store.
  const int myh = mh;
#pragma unroll
  for (int h = 0; h < 2; h++) {
    if (myh == h) {
#pragma unroll
      for (int i = 0; i < 8; i++) {
        float rs[4];
#pragma unroll
        for (int r = 0; r < 4; r++) rs[r] = 0.0f;
#pragma unroll
        for (int j = 0; j < 4; j++) {
          const int col = wn + j * 16 + ln;  // 0..255 within tile
          const int gcol = n0 + col;
#pragma unroll
          for (int r = 0; r < 4; r++) {
            const int row = i * 16 + quad * 4 + r;  // 0..127 within half
            const int grow = m0 + h * 128 + row;
            float p = 0.0f;
            if (gcol <= grow) p = __expf(acc[i][j][r] * scale);
            const ushort pk = f2bf(p);
            smem[row * 256 + (col ^ ((row & 7) << 3))] = pk;
            rs[r] += bf2f(pk);
          }
        }
#pragma unroll
        for (int r = 0; r < 4; r++) {
          float s = rs[r];
          s += __shfl_xor(s, 1);
          s += __shfl_xor(s, 2);
          s += __shfl_xor(s, 4);
          s += __shfl_xor(s, 8);
          if (ln == 0)
            atomicAdd(ls + b * SEQ + m0 + h * 128 + i * 16 + quad * 4 + r, s);
        }
      }
    }
    __syncthreads();
    const int mtr = 2 * mt + h;  // 128-granularity tile row
    ushort* pt0 = pb + ((size_t)(b * 528 + mtr * (mtr + 1) / 2 + 2 * nt) << 14);
    ushort* pt1 = pt0 + (1 << 14);
    const bool st1 = (2 * nt + 1) <= mtr;  // right 128-subtile exists?
#pragma unroll
    for (int p = 0; p < 8; p++) {
      const int tt = p * 512 + tid;  // 0..4095 16B-slots
      const int row = tt >> 5;
      const int cs = tt & 31;
      ushort8 v = *(const ushort8*)&smem[row * 256 + ((cs * 8) ^ ((row & 7) << 3))];
      if (cs < 16) {
        *(ushort8*)(pt0 + row * 128 + cs * 8) = v;
      } else if (st1) {
        *(ushort8*)(pt1 + row * 128 + (cs - 16) * 8) = v;
      }
    }
    __syncthreads();
  }
}

// ---------- kernel 3: O = P_hat @ V, divide by l (BK=64, serpentine) ----------
__global__ __launch_bounds__(256, 4)
void attn_pv(const ushort* __restrict__ pb, const ushort* __restrict__ vt,
             const float* __restrict__ ls, float* __restrict__ out) {
  __shared__ ushort smem[16384];
  ushort* As = smem;
  ushort* Bs = smem + 8192;

  // serpentine rank -> (mt desc, et, b): balances per-CU work at 3 blocks/CU
  int idx = blockIdx.x;
  int chunk = idx >> 8, pos = idx & 255;
  if (chunk & 1) pos = 255 - pos;
  const int r_ = (chunk << 8) + pos;
  const int mt = 31 - r_ / 24;
  const int rem = r_ % 24;
  const int b = rem & 3;
  const int et = rem >> 2;
  const int m0 = mt * 128, e0 = et * 128;

  const int tid = threadIdx.x;
  const int w = tid >> 6, lane = tid & 63, ln = lane & 15, quad = lane >> 4;
  const int wm = (w >> 1) * 64, wn = (w & 1) * 64;
  const size_t vtbase = (size_t)b * DIM * SEQ;
  const ushort* ptiles = pb + ((size_t)(b * 528 + mt * (mt + 1) / 2) << 14);

  const int c0 = w * 128 + lane;
  const int c1 = c0 + 64;
  const int R0 = c0 >> 2, kl0 = (c0 & 3) ^ ((R0 >> 1) & 3);
  const int R1 = c1 >> 2, kl1 = (c1 & 3) ^ ((R1 >> 1) & 3);
  const ushort* ag0 = ptiles + R0 * 128 + kl0 * 8;
  const ushort* ag1 = ptiles + R1 * 128 + kl1 * 8;
  const ushort* bg0 = vt + vtbase + (size_t)(e0 + R0) * SEQ + kl0 * 8;
  const ushort* bg1 = vt + vtbase + (size_t)(e0 + R1) * SEQ + kl1 * 8;
  ushort* al0 = As + (size_t)(w * 128) * 8;
  ushort* al1 = As + (size_t)(w * 128 + 64) * 8;
  ushort* bl0 = Bs + (size_t)(w * 128) * 8;
  ushort* bl1 = Bs + (size_t)(w * 128 + 64) * 8;

  const int sw = quad ^ ((ln >> 1) & 3);
  int aoff[4], boff[4];
#pragma unroll
  for (int i = 0; i < 4; i++) aoff[i] = ((wm + i * 16 + ln) * 4 + sw) * 8;
#pragma unroll
  for (int i = 0; i < 4; i++) boff[i] = ((wn + i * 16 + ln) * 4 + sw) * 8;

  fx4 acc[4][4];
#pragma unroll
  for (int i = 0; i < 4; i++)
#pragma unroll
    for (int j = 0; j < 4; j++) acc[i][j] = (fx4)0.0f;

  const int nk = (mt + 1) * 2;  // 64-wide k-steps
  for (int ks = 0; ks < nk; ks++) {
    const int ntile = ks >> 1;
    const int kin = (ks & 1) * 64;
    const size_t atile = (size_t)ntile * 16384 + kin;
    const int kglob = ntile * 128 + kin;
    gload_lds16(ag0 + atile, al0);
    gload_lds16(ag1 + atile, al1);
    gload_lds16(ag0 + atile + 32, al0 + 4096);
    gload_lds16(ag1 + atile + 32, al1 + 4096);
    gload_lds16(bg0 + kglob, bl0);
    gload_lds16(bg1 + kglob, bl1);
    gload_lds16(bg0 + kglob + 32, bl0 + 4096);
    gload_lds16(bg1 + kglob + 32, bl1 + 4096);
    __syncthreads();
#pragma unroll
    for (int h = 0; h < 2; h++) {
      const int hb = h * 4096;
      short8 af[4], bf[4];
#pragma unroll
      for (int i = 0; i < 4; i++) af[i] = *(const short8*)(As + hb + aoff[i]);
#pragma unroll
      for (int i = 0; i < 4; i++) bf[i] = *(const short8*)(Bs + hb + boff[i]);
#pragma unroll
      for (int i = 0; i < 4; i++)
#pragma unroll
        for (int j = 0; j < 4; j++)
          acc[i][j] = MFMA16(af[i], bf[j], acc[i][j]);
    }
    __syncthreads();
  }

#pragma unroll
  for (int i = 0; i < 4; i++)
#pragma unroll
    for (int r = 0; r < 4; r++) {
      const int row = m0 + wm + i * 16 + quad * 4 + r;
      const float linv = 1.0f / ls[b * SEQ + row];
      float* orow = out + ((size_t)(b * SEQ + row)) * DIM + e0 + wn + ln;
#pragma unroll
      for (int j = 0; j < 4; j++) orow[j * 16] = acc[i][j][r] * linv;
    }
}

extern "C" void kernel_launch(void* const* d_in, const int* in_sizes, int n_in,
                              void* d_out, int out_size, void* d_ws, size_t ws_size,
                              hipStream_t stream) {
  const float* x = (const float*)d_in[0];
  const float* wq = (const float*)d_in[1];
  const float* wk = (const float*)d_in[2];
  const float* wv = (const float*)d_in[3];
  float* out = (float*)d_out;

  ushort* qb = (ushort*)d_ws;
  ushort* kb = qb + 12582912;
  ushort* vt = kb + 12582912;
  ushort* xb = vt + 12582912;
  ushort* wb = xb + 12582912;
  ushort* pb = xb;  // alias: xb/wb dead after qkv_proj
  float* ls = (float*)((ushort*)d_ws + 72351744);

  cvt_all<<<7008, 256, 0, stream>>>(x, wq, wk, wv, xb, wb, ls);
  qkv_proj<<<dim3(128, 18), 256, 0, stream>>>(xb, wb, qb, kb, vt);
  attn_scores<<<dim3(544), 512, 0, stream>>>(qb, kb, pb, ls);
  attn_pv<<<768, 256, 0, stream>>>(pb, vt, ls, out);
}

// Round 5
// 330.418 us; speedup vs baseline: 2.9423x; 1.1301x over previous
//
#include <hip/hip_runtime.h>
#include <stdint.h>

// SelfAttention: B=4, S=4096, D=768, causal, fp32 in/out, bf16 MFMA compute.
// Decomposition: cvt -> qkv GEMM -> scores GEMM (+exp epilogue, packed causal
// P tiles) -> PV GEMM (/l epilogue). All GEMMs: 128x128 tile, BK=64 (two
// BK=32 XOR-swizzled panels per barrier pair), global_load_lds width-16.
// Round-5: attn_scores tile index gets a bijective XCD swizzle (528 = 8*66):
// consecutive triangle tiles (sharing Q/K panels) land on one XCD's L2.
// NOTE (rounds 1-4 post-mortems): 256^2 tile + counted-vmcnt / m201-style
// 8-phase schedules all measured ~11-12 CU-us per 128^2-tile -- same as this
// 2-barrier structure -- and cost 36 us net. Do not revisit without disasm.
// Also: launch_bounds min-waves>2 on the 512-thr variant spilled acc to
// scratch (2.5 GB). This file is the measured-best structure (round 0).
// ws layout (bf16 elements):
//   qb  12582912 @ 0
//   kb  12582912 @ 12582912
//   vt  12582912 @ 25165824   [b][e][s] (V transposed)
//   xb  12582912 @ 37748736   (dead after qkv_proj)
//   wb   1769472 @ 50331648   (dead after qkv_proj)
//   pb  34603008 @ 37748736   ALIAS over xb/wb: packed causal P tiles,
//                             tile (b, mt, nt<=mt) at slot b*528+mt(mt+1)/2+nt
//   ls  16384 fp32 @ elem 72351744
#define SEQ 4096
#define DIM 768

typedef __attribute__((ext_vector_type(8))) short short8;
typedef __attribute__((ext_vector_type(8))) unsigned short ushort8;
typedef __attribute__((ext_vector_type(4))) unsigned short ushort4v;
typedef __attribute__((ext_vector_type(4))) float fx4;
typedef unsigned short ushort;

#define MFMA16(a, b, c) __builtin_amdgcn_mfma_f32_16x16x32_bf16((a), (b), (c), 0, 0, 0)

__device__ __forceinline__ ushort f2bf(float f) {
  union { float f; unsigned int u; } v; v.f = f;
  return (ushort)((v.u + 0x7fffu + ((v.u >> 16) & 1u)) >> 16);
}
__device__ __forceinline__ float bf2f(ushort u) {
  union { unsigned int u; float f; } v; v.u = ((unsigned int)u) << 16;
  return v.f;
}
__device__ __forceinline__ void gload_lds16(const ushort* g, ushort* l) {
  __builtin_amdgcn_global_load_lds(
      (const __attribute__((address_space(1))) void*)g,
      (__attribute__((address_space(3))) void*)l, 16, 0, 0);
}

// ---------- kernel 0: fused fp32->bf16 casts + ls zero ----------
__global__ void cvt_all(const float* __restrict__ x, const float* __restrict__ wq,
                        const float* __restrict__ wk, const float* __restrict__ wv,
                        ushort* __restrict__ xb, ushort* __restrict__ wb,
                        float* __restrict__ ls) {
  const int bid = blockIdx.x;
  if (bid < 6144) {
    if (bid < 64) ls[bid * 256 + threadIdx.x] = 0.0f;
    const int i = (bid * 256 + threadIdx.x) * 8;
    fx4 a = *(const fx4*)(x + i);
    fx4 b = *(const fx4*)(x + i + 4);
    ushort8 o;
#pragma unroll
    for (int c = 0; c < 4; c++) { o[c] = f2bf(a[c]); o[c + 4] = f2bf(b[c]); }
    *(ushort8*)(xb + i) = o;
  } else {
    const int i = ((bid - 6144) * 256 + threadIdx.x) * 8;
    const int which = i / (DIM * DIM);
    const int off = i - which * (DIM * DIM);
    const float* src = (which == 0) ? wq : (which == 1) ? wk : wv;
    fx4 a = *(const fx4*)(src + off);
    fx4 b = *(const fx4*)(src + off + 4);
    ushort8 o;
#pragma unroll
    for (int c = 0; c < 4; c++) { o[c] = f2bf(a[c]); o[c + 4] = f2bf(b[c]); }
    *(ushort8*)(wb + i) = o;
  }
}

// ---------- kernel 1: QKV projection (128x128 tile, BK=64) ----------
__global__ __launch_bounds__(256, 4)
void qkv_proj(const ushort* __restrict__ xb, const ushort* __restrict__ wb,
              ushort* __restrict__ qb, ushort* __restrict__ kb,
              ushort* __restrict__ vt) {
  __shared__ ushort smem[17408];  // k-loop: As[8192]|Bs[8192]; epilogue 128x136
  ushort* As = smem;
  ushort* Bs = smem + 8192;

  const int mb = blockIdx.x, nb = blockIdx.y;
  const int which = nb / 6;
  const int e0 = (nb % 6) * 128;
  const int m0 = mb * 128;
  const int tid = threadIdx.x;
  const int w = tid >> 6, lane = tid & 63, ln = lane & 15, quad = lane >> 4;
  const int wm = (w >> 1) * 64, wn = (w & 1) * 64;

  const ushort* W = wb + (size_t)which * (DIM * DIM);

  // per-panel staging: chunk c -> row R=c>>2, k-group kl=(c&3)^((R>>1)&3)
  const int c0 = w * 128 + lane;
  const int c1 = c0 + 64;
  const int R0 = c0 >> 2, kl0 = (c0 & 3) ^ ((R0 >> 1) & 3);
  const int R1 = c1 >> 2, kl1 = (c1 & 3) ^ ((R1 >> 1) & 3);
  const ushort* ag0 = xb + (size_t)(m0 + R0) * DIM + kl0 * 8;
  const ushort* ag1 = xb + (size_t)(m0 + R1) * DIM + kl1 * 8;
  const ushort* bg0 = W + (size_t)(e0 + R0) * DIM + kl0 * 8;
  const ushort* bg1 = W + (size_t)(e0 + R1) * DIM + kl1 * 8;
  ushort* al0 = As + (size_t)(w * 128) * 8;
  ushort* al1 = As + (size_t)(w * 128 + 64) * 8;
  ushort* bl0 = Bs + (size_t)(w * 128) * 8;
  ushort* bl1 = Bs + (size_t)(w * 128 + 64) * 8;

  const int sw = quad ^ ((ln >> 1) & 3);
  int aoff[4], boff[4];
#pragma unroll
  for (int i = 0; i < 4; i++) aoff[i] = ((wm + i * 16 + ln) * 4 + sw) * 8;
#pragma unroll
  for (int i = 0; i < 4; i++) boff[i] = ((wn + i * 16 + ln) * 4 + sw) * 8;

  fx4 acc[4][4];
#pragma unroll
  for (int i = 0; i < 4; i++)
#pragma unroll
    for (int j = 0; j < 4; j++) acc[i][j] = (fx4)0.0f;

  for (int kk = 0; kk < DIM; kk += 64) {
    gload_lds16(ag0 + kk, al0);
    gload_lds16(ag1 + kk, al1);
    gload_lds16(ag0 + kk + 32, al0 + 4096);
    gload_lds16(ag1 + kk + 32, al1 + 4096);
    gload_lds16(bg0 + kk, bl0);
    gload_lds16(bg1 + kk, bl1);
    gload_lds16(bg0 + kk + 32, bl0 + 4096);
    gload_lds16(bg1 + kk + 32, bl1 + 4096);
    __syncthreads();
#pragma unroll
    for (int h = 0; h < 2; h++) {
      const int hb = h * 4096;
      short8 af[4], bf[4];
#pragma unroll
      for (int i = 0; i < 4; i++) af[i] = *(const short8*)(As + hb + aoff[i]);
#pragma unroll
      for (int i = 0; i < 4; i++) bf[i] = *(const short8*)(Bs + hb + boff[i]);
#pragma unroll
      for (int i = 0; i < 4; i++)
#pragma unroll
        for (int j = 0; j < 4; j++)
          acc[i][j] = MFMA16(af[i], bf[j], acc[i][j]);
    }
    __syncthreads();
  }

  if (which == 2) {
#pragma unroll
    for (int i = 0; i < 4; i++)
#pragma unroll
      for (int j = 0; j < 4; j++) {
        const int s = m0 + wm + i * 16 + quad * 4;
        const int e = e0 + wn + j * 16 + ln;
        const int bb = s >> 12, si = s & 4095;
        ushort4v p;
#pragma unroll
        for (int r = 0; r < 4; r++) p[r] = f2bf(acc[i][j][r]);
        *(ushort4v*)(vt + ((size_t)bb * DIM + e) * SEQ + si) = p;
      }
  } else {
#pragma unroll
    for (int i = 0; i < 4; i++)
#pragma unroll
      for (int j = 0; j < 4; j++)
#pragma unroll
        for (int r = 0; r < 4; r++)
          smem[(wm + i * 16 + quad * 4 + r) * 136 + wn + j * 16 + ln] =
              f2bf(acc[i][j][r]);
    __syncthreads();
    ushort* dst = (which == 0) ? qb : kb;
#pragma unroll
    for (int p = 0; p < 8; p++) {
      const int tt = p * 256 + tid;
      const int row = tt >> 4, col = (tt & 15) * 8;
      ushort8 v = *(const ushort8*)&smem[row * 136 + col];
      *(ushort8*)(dst + (size_t)(m0 + row) * DIM + e0 + col) = v;
    }
  }
}

// ---------- kernel 2: scores GEMM + exp epilogue (BK=64) ----------
__global__ __launch_bounds__(256, 4)
void attn_scores(const ushort* __restrict__ qb, const ushort* __restrict__ kb,
                 ushort* __restrict__ pb, float* __restrict__ ls) {
  __shared__ ushort smem[17408];
  ushort* As = smem;
  ushort* Bs = smem + 8192;

  // XCD-bijective tile order: 528 = 8*66; gridDim.x stripe per b is 528
  // (divisible by 8), so blockIdx.x % 8 == dispatch-linear id % 8 == XCD.
  // Each XCD gets 66 consecutive triangle tiles -> Q/K panel reuse in its L2.
  const int x0 = blockIdx.x;
  const int pr = (x0 & 7) * 66 + (x0 >> 3);
  const int b = blockIdx.y;
  int mt = (int)(0.5f * (sqrtf(8.0f * pr + 1.0f) - 1.0f));
  while ((mt + 1) * (mt + 2) / 2 <= pr) ++mt;
  while (mt * (mt + 1) / 2 > pr) --mt;
  const int nt = pr - mt * (mt + 1) / 2;
  const int m0 = mt * 128, n0 = nt * 128;

  const int tid = threadIdx.x;
  const int w = tid >> 6, lane = tid & 63, ln = lane & 15, quad = lane >> 4;
  const int wm = (w >> 1) * 64, wn = (w & 1) * 64;
  const size_t qkbase = (size_t)b * SEQ * DIM;
  const float scale = 0.03608439182435161f;  // 1/sqrt(768)

  const int c0 = w * 128 + lane;
  const int c1 = c0 + 64;
  const int R0 = c0 >> 2, kl0 = (c0 & 3) ^ ((R0 >> 1) & 3);
  const int R1 = c1 >> 2, kl1 = (c1 & 3) ^ ((R1 >> 1) & 3);
  const ushort* ag0 = qb + qkbase + (size_t)(m0 + R0) * DIM + kl0 * 8;
  const ushort* ag1 = qb + qkbase + (size_t)(m0 + R1) * DIM + kl1 * 8;
  const ushort* bg0 = kb + qkbase + (size_t)(n0 + R0) * DIM + kl0 * 8;
  const ushort* bg1 = kb + qkbase + (size_t)(n0 + R1) * DIM + kl1 * 8;
  ushort* al0 = As + (size_t)(w * 128) * 8;
  ushort* al1 = As + (size_t)(w * 128 + 64) * 8;
  ushort* bl0 = Bs + (size_t)(w * 128) * 8;
  ushort* bl1 = Bs + (size_t)(w * 128 + 64) * 8;

  const int sw = quad ^ ((ln >> 1) & 3);
  int aoff[4], boff[4];
#pragma unroll
  for (int i = 0; i < 4; i++) aoff[i] = ((wm + i * 16 + ln) * 4 + sw) * 8;
#pragma unroll
  for (int i = 0; i < 4; i++) boff[i] = ((wn + i * 16 + ln) * 4 + sw) * 8;

  fx4 acc[4][4];
#pragma unroll
  for (int i = 0; i < 4; i++)
#pragma unroll
    for (int j = 0; j < 4; j++) acc[i][j] = (fx4)0.0f;

  for (int kk = 0; kk < DIM; kk += 64) {
    gload_lds16(ag0 + kk, al0);
    gload_lds16(ag1 + kk, al1);
    gload_lds16(ag0 + kk + 32, al0 + 4096);
    gload_lds16(ag1 + kk + 32, al1 + 4096);
    gload_lds16(bg0 + kk, bl0);
    gload_lds16(bg1 + kk, bl1);
    gload_lds16(bg0 + kk + 32, bl0 + 4096);
    gload_lds16(bg1 + kk + 32, bl1 + 4096);
    __syncthreads();
#pragma unroll
    for (int h = 0; h < 2; h++) {
      const int hb = h * 4096;
      short8 af[4], bf[4];
#pragma unroll
      for (int i = 0; i < 4; i++) af[i] = *(const short8*)(As + hb + aoff[i]);
#pragma unroll
      for (int i = 0; i < 4; i++) bf[i] = *(const short8*)(Bs + hb + boff[i]);
#pragma unroll
      for (int i = 0; i < 4; i++)
#pragma unroll
        for (int j = 0; j < 4; j++)
          acc[i][j] = MFMA16(af[i], bf[j], acc[i][j]);
    }
    __syncthreads();
  }

  // epilogue: exp + causal mask + row sums + pack via LDS
  float rowp[4][4];
#pragma unroll
  for (int i = 0; i < 4; i++) {
#pragma unroll
    for (int r = 0; r < 4; r++) rowp[i][r] = 0.0f;
#pragma unroll
    for (int j = 0; j < 4; j++) {
      const int col = n0 + wn + j * 16 + ln;
#pragma unroll
      for (int r = 0; r < 4; r++) {
        const int row = m0 + wm + i * 16 + quad * 4 + r;
        float p = 0.0f;
        if (col <= row) p = __expf(acc[i][j][r] * scale);
        const ushort pk = f2bf(p);
        smem[(wm + i * 16 + quad * 4 + r) * 136 + wn + j * 16 + ln] = pk;
        rowp[i][r] += bf2f(pk);
      }
    }
  }
#pragma unroll
  for (int i = 0; i < 4; i++)
#pragma unroll
    for (int r = 0; r < 4; r++) {
      float s = rowp[i][r];
      s += __shfl_xor(s, 1);
      s += __shfl_xor(s, 2);
      s += __shfl_xor(s, 4);
      s += __shfl_xor(s, 8);
      if (ln == 0)
        atomicAdd(ls + b * SEQ + m0 + wm + i * 16 + quad * 4 + r, s);
    }
  __syncthreads();
  ushort* pt = pb + ((size_t)(b * 528 + pr) << 14);
#pragma unroll
  for (int p = 0; p < 8; p++) {
    const int tt = p * 256 + tid;
    const int row = tt >> 4, col = (tt & 15) * 8;
    ushort8 v = *(const ushort8*)&smem[row * 136 + col];
    *(ushort8*)(pt + row * 128 + col) = v;
  }
}

// ---------- kernel 3: O = P_hat @ V, divide by l (BK=64, serpentine) ----------
__global__ __launch_bounds__(256, 4)
void attn_pv(const ushort* __restrict__ pb, const ushort* __restrict__ vt,
             const float* __restrict__ ls, float* __restrict__ out) {
  __shared__ ushort smem[16384];
  ushort* As = smem;
  ushort* Bs = smem + 8192;

  // serpentine rank -> (mt desc, et, b): balances per-CU work at 3 blocks/CU
  int idx = blockIdx.x;
  int chunk = idx >> 8, pos = idx & 255;
  if (chunk & 1) pos = 255 - pos;
  const int r_ = (chunk << 8) + pos;
  const int mt = 31 - r_ / 24;
  const int rem = r_ % 24;
  const int b = rem & 3;
  const int et = rem >> 2;
  const int m0 = mt * 128, e0 = et * 128;

  const int tid = threadIdx.x;
  const int w = tid >> 6, lane = tid & 63, ln = lane & 15, quad = lane >> 4;
  const int wm = (w >> 1) * 64, wn = (w & 1) * 64;
  const size_t vtbase = (size_t)b * DIM * SEQ;
  const ushort* ptiles = pb + ((size_t)(b * 528 + mt * (mt + 1) / 2) << 14);

  const int c0 = w * 128 + lane;
  const int c1 = c0 + 64;
  const int R0 = c0 >> 2, kl0 = (c0 & 3) ^ ((R0 >> 1) & 3);
  const int R1 = c1 >> 2, kl1 = (c1 & 3) ^ ((R1 >> 1) & 3);
  const ushort* ag0 = ptiles + R0 * 128 + kl0 * 8;
  const ushort* ag1 = ptiles + R1 * 128 + kl1 * 8;
  const ushort* bg0 = vt + vtbase + (size_t)(e0 + R0) * SEQ + kl0 * 8;
  const ushort* bg1 = vt + vtbase + (size_t)(e0 + R1) * SEQ + kl1 * 8;
  ushort* al0 = As + (size_t)(w * 128) * 8;
  ushort* al1 = As + (size_t)(w * 128 + 64) * 8;
  ushort* bl0 = Bs + (size_t)(w * 128) * 8;
  ushort* bl1 = Bs + (size_t)(w * 128 + 64) * 8;

  const int sw = quad ^ ((ln >> 1) & 3);
  int aoff[4], boff[4];
#pragma unroll
  for (int i = 0; i < 4; i++) aoff[i] = ((wm + i * 16 + ln) * 4 + sw) * 8;
#pragma unroll
  for (int i = 0; i < 4; i++) boff[i] = ((wn + i * 16 + ln) * 4 + sw) * 8;

  fx4 acc[4][4];
#pragma unroll
  for (int i = 0; i < 4; i++)
#pragma unroll
    for (int j = 0; j < 4; j++) acc[i][j] = (fx4)0.0f;

  const int nk = (mt + 1) * 2;  // 64-wide k-steps
  for (int ks = 0; ks < nk; ks++) {
    const int ntile = ks >> 1;
    const int kin = (ks & 1) * 64;
    const size_t atile = (size_t)ntile * 16384 + kin;
    const int kglob = ntile * 128 + kin;
    gload_lds16(ag0 + atile, al0);
    gload_lds16(ag1 + atile, al1);
    gload_lds16(ag0 + atile + 32, al0 + 4096);
    gload_lds16(ag1 + atile + 32, al1 + 4096);
    gload_lds16(bg0 + kglob, bl0);
    gload_lds16(bg1 + kglob, bl1);
    gload_lds16(bg0 + kglob + 32, bl0 + 4096);
    gload_lds16(bg1 + kglob + 32, bl1 + 4096);
    __syncthreads();
#pragma unroll
    for (int h = 0; h < 2; h++) {
      const int hb = h * 4096;
      short8 af[4], bf[4];
#pragma unroll
      for (int i = 0; i < 4; i++) af[i] = *(const short8*)(As + hb + aoff[i]);
#pragma unroll
      for (int i = 0; i < 4; i++) bf[i] = *(const short8*)(Bs + hb + boff[i]);
#pragma unroll
      for (int i = 0; i < 4; i++)
#pragma unroll
        for (int j = 0; j < 4; j++)
          acc[i][j] = MFMA16(af[i], bf[j], acc[i][j]);
    }
    __syncthreads();
  }

#pragma unroll
  for (int i = 0; i < 4; i++)
#pragma unroll
    for (int r = 0; r < 4; r++) {
      const int row = m0 + wm + i * 16 + quad * 4 + r;
      const float linv = 1.0f / ls[b * SEQ + row];
      float* orow = out + ((size_t)(b * SEQ + row)) * DIM + e0 + wn + ln;
#pragma unroll
      for (int j = 0; j < 4; j++) orow[j * 16] = acc[i][j][r] * linv;
    }
}

extern "C" void kernel_launch(void* const* d_in, const int* in_sizes, int n_in,
                              void* d_out, int out_size, void* d_ws, size_t ws_size,
                              hipStream_t stream) {
  const float* x = (const float*)d_in[0];
  const float* wq = (const float*)d_in[1];
  const float* wk = (const float*)d_in[2];
  const float* wv = (const float*)d_in[3];
  float* out = (float*)d_out;

  ushort* qb = (ushort*)d_ws;
  ushort* kb = qb + 12582912;
  ushort* vt = kb + 12582912;
  ushort* xb = vt + 12582912;
  ushort* wb = xb + 12582912;
  ushort* pb = xb;  // alias: xb/wb dead after qkv_proj
  float* ls = (float*)((ushort*)d_ws + 72351744);

  cvt_all<<<7008, 256, 0, stream>>>(x, wq, wk, wv, xb, wb, ls);
  qkv_proj<<<dim3(128, 18), 256, 0, stream>>>(xb, wb, qb, kb, vt);
  attn_scores<<<dim3(528, 4), 256, 0, stream>>>(qb, kb, pb, ls);
  attn_pv<<<768, 256, 0, stream>>>(pb, vt, ls, out);
}